// Round 6
// baseline (126.308 us; speedup 1.0000x reference)
//
#include <hip/hip_runtime.h>
#include <hip/hip_fp16.h>

// N=1536 T=20 H=64 E=16 M=128
// pre1[i,j] = Q[j] - P[i]  (Q,P: N x 128 fp16 in d_ws; W2T: 64x128 fp16 in d_ws)
// out[i]    = max_j relu( relu(Q[j]-P[i]) @ W2 + b2 )
//
// R6: register diet to cross the 3-waves/SIMD threshold (<=168 regs):
// NI 3->2 (pv 48->32, acc 48->32), q double-buffer dropped (-16, TLP from
// 3 waves/SIMD covers L2 latency), rolled t-loop w/ pointer increment,
// explicit half2 packed prep (guarantee v_pk_sub/max_f16), JSPLIT=8
// (6144 blocks = 24/CU = 2 clean generations at 12 resident waves/CU).
// R5 evidence: VALUBusy 3.7x hand-count + occupancy pinned at 2/SIMD
// regardless of grid => allocator churn from ~190+ live regs.

#define NN 1536
#define HH 64
#define EE 16
#define MM 128
#define TT 20
#define NI 2
#define JSPLIT 8
#define NIGRP (NN / NI)      // 768 i-groups
#define NTILE (96 / JSPLIT)  // 12 j-tiles of 16 per wave

typedef _Float16 half8 __attribute__((ext_vector_type(8)));
typedef _Float16 half2v __attribute__((ext_vector_type(2)));
typedef float f32x4 __attribute__((ext_vector_type(4)));

union H8 { half8 v; half2v h2[4]; };

// grid NN, block 128. Computes Q,P,W2T (fp16) and zero-inits out (poisoned 0xAA).
__global__ __launch_bounds__(128) void precompute_kernel(
    const float* __restrict__ hidden, const float* __restrict__ gt,
    const float* __restrict__ We, const float* __restrict__ be,
    const float* __restrict__ W1, const float* __restrict__ b1,
    const float* __restrict__ W2,
    _Float16* __restrict__ Q, _Float16* __restrict__ P,
    _Float16* __restrict__ W2T, float* __restrict__ out)
{
  const int j = blockIdx.x;
  const int m = threadIdx.x;
  const float* hrow = hidden + j * HH;
  float a = 0.f;
  #pragma unroll 8
  for (int h = 0; h < HH; ++h) a = fmaf(hrow[h], W1[h * MM + m], a);
  float ve0 = 0.f, ve1 = 0.f, cm = b1[m];
  #pragma unroll
  for (int e = 0; e < EE; ++e) {
    float w1e = W1[(HH + e) * MM + m];
    ve0 = fmaf(We[e], w1e, ve0);       // We[0][e]
    ve1 = fmaf(We[EE + e], w1e, ve1);  // We[1][e]
    cm  = fmaf(be[e], w1e, cm);
  }
  const float e0 = gt[j * (2 * TT) + 2 * (TT - 1)];
  const float e1 = gt[j * (2 * TT) + 2 * (TT - 1) + 1];
  const float p = fmaf(e0, ve0, e1 * ve1);
  P[j * MM + m] = (_Float16)p;
  Q[j * MM + m] = (_Float16)(a + p + cm);
  if (j < HH) W2T[j * MM + m] = (_Float16)W2[m * HH + j];  // W2T[col][k]
  if (m < HH) out[j * HH + m] = 0.f;
}

// grid NIGRP*JSPLIT (=6144), block 64 (1 wave). Wave: i0,i0+1, 12 j-tiles.
// (64,3): estimated live set ~158 regs fits the ~168 cap for 3 waves/SIMD.
// (R2 lesson applies when cap << live set; here the gap is ~ -10.)
__global__ __launch_bounds__(64, 3) void pairmlp_max_kernel(
    const _Float16* __restrict__ Q, const _Float16* __restrict__ P,
    const _Float16* __restrict__ W2T, const float* __restrict__ b2,
    float* __restrict__ out)
{
  const int lane = threadIdx.x;
  const int quad = lane >> 4;   // 0..3
  const int lcol = lane & 15;
  const int ig = blockIdx.x % NIGRP;
  const int js = blockIdx.x / NIGRP;
  const int i0 = ig * NI;

  // B fragments from fp16 W2T: bfrag[ct][ks] = W2T[ct*16+lcol][ks*32+quad*8 ..+8]
  half8 bfrag[4][4];
  #pragma unroll
  for (int ct = 0; ct < 4; ++ct) {
    const _Float16* wrow = W2T + (ct * 16 + lcol) * MM + quad * 8;
    #pragma unroll
    for (int ks = 0; ks < 4; ++ks)
      bfrag[ct][ks] = *(const half8*)(wrow + ks * 32);
  }

  // P fragments for NI i's: lane's A-frag k-slots (8 halfs per ks)
  H8 pv[NI][4];
  #pragma unroll
  for (int ii = 0; ii < NI; ++ii) {
    const _Float16* prow = P + (i0 + ii) * MM + quad * 8;
    #pragma unroll
    for (int ks = 0; ks < 4; ++ks)
      pv[ii][ks].v = *(const half8*)(prow + ks * 32);
  }

  float rmax[NI][4];
  #pragma unroll
  for (int ii = 0; ii < NI; ++ii)
    #pragma unroll
    for (int ct = 0; ct < 4; ++ct) rmax[ii][ct] = -1e30f;

  const int jt0 = js * NTILE;
  const _Float16* qptr = Q + (jt0 * 16 + lcol) * MM + quad * 8;

  const half2v hz2 = {(_Float16)0.f, (_Float16)0.f};
  const f32x4 zc = {0.f, 0.f, 0.f, 0.f};

  #pragma unroll 1
  for (int t = 0; t < NTILE; ++t) {
    H8 q[4];
    #pragma unroll
    for (int ks = 0; ks < 4; ++ks)
      q[ks].v = *(const half8*)(qptr + ks * 32);
    qptr += 16 * MM;

    f32x4 acc[NI][4];
    #pragma unroll
    for (int ks = 0; ks < 4; ++ks) {
      #pragma unroll
      for (int ii = 0; ii < NI; ++ii) {
        // A-frag = relu(q - p): explicit half2 packed (v_pk_sub_f16 + v_pk_max_f16)
        H8 s;
        #pragma unroll
        for (int r = 0; r < 4; ++r) {
          half2v d = q[ks].h2[r] - pv[ii][ks].h2[r];
          s.h2[r] = __builtin_elementwise_max(d, hz2);
        }
        if (ks == 0) {
          #pragma unroll
          for (int ct = 0; ct < 4; ++ct)
            acc[ii][ct] = __builtin_amdgcn_mfma_f32_16x16x32_f16(s.v, bfrag[ct][0], zc, 0, 0, 0);
        } else {
          #pragma unroll
          for (int ct = 0; ct < 4; ++ct)
            acc[ii][ct] = __builtin_amdgcn_mfma_f32_16x16x32_f16(s.v, bfrag[ct][ks], acc[ii][ct], 0, 0, 0);
        }
      }
    }

    // C/D: col=lcol(+ct*16), row(j)=quad*4+reg. max3-friendly reduction.
    #pragma unroll
    for (int ii = 0; ii < NI; ++ii)
      #pragma unroll
      for (int ct = 0; ct < 4; ++ct) {
        const float m01 = fmaxf(acc[ii][ct][0], acc[ii][ct][1]);
        const float m23 = fmaxf(acc[ii][ct][2], acc[ii][ct][3]);
        rmax[ii][ct] = fmaxf(rmax[ii][ct], fmaxf(m01, m23));
      }
  }

  // combine quad-groups (different j rows, same col), then b2 + relu + atomic max
  #pragma unroll
  for (int ii = 0; ii < NI; ++ii)
    #pragma unroll
    for (int ct = 0; ct < 4; ++ct) {
      float v = rmax[ii][ct];
      v = fmaxf(v, __shfl_xor(v, 16, 64));
      v = fmaxf(v, __shfl_xor(v, 32, 64));
      v = fmaxf(v + b2[ct * 16 + lcol], 0.f);
      if (quad == 0)
        atomicMax((unsigned*)(out + (i0 + ii) * HH + ct * 16 + lcol), __float_as_uint(v));
    }
}

extern "C" void kernel_launch(void* const* d_in, const int* in_sizes, int n_in,
                              void* d_out, int out_size, void* d_ws, size_t ws_size,
                              hipStream_t stream) {
  const float* hidden = (const float*)d_in[0];
  const float* gt     = (const float*)d_in[1];
  const float* We     = (const float*)d_in[2];
  const float* be     = (const float*)d_in[3];
  const float* W1     = (const float*)d_in[4];
  const float* b1     = (const float*)d_in[5];
  const float* W2     = (const float*)d_in[6];
  const float* b2     = (const float*)d_in[7];
  float* out = (float*)d_out;

  _Float16* Qh  = (_Float16*)d_ws;    // NN*MM fp16 (384KB)
  _Float16* Ph  = Qh + NN * MM;       // NN*MM fp16 (384KB)
  _Float16* W2T = Ph + NN * MM;       // HH*MM fp16 (16KB)

  precompute_kernel<<<NN, 128, 0, stream>>>(hidden, gt, We, be, W1, b1, W2, Qh, Ph, W2T, out);
  pairmlp_max_kernel<<<NIGRP * JSPLIT, 64, 0, stream>>>(Qh, Ph, W2T, b2, out);
}